// Round 17
// baseline (142.329 us; speedup 1.0000x reference)
//
#include <hip/hip_runtime.h>

typedef float f32x4 __attribute__((ext_vector_type(4)));
typedef int   int4v __attribute__((ext_vector_type(4)));
typedef int   int8v __attribute__((ext_vector_type(8)));

#define AS1 __attribute__((address_space(1)))
#define AS3 __attribute__((address_space(3)))

#define NROWS 2048
#define NCOLS 100000
#define NPAD  100352              // 98 chunks * 1024
#define NCHUNK 98
#define K2C  28.853900817779268f  // 20 * log2(e)
#define PADC 7.2552607e-7f        // 352 * exp(-20): pad-column bias
#define SCLA 0x7F7F7F7Fu          // E8M0 scale 2^0  (A already x K2C)
#define SCLB 0x7C7C7C7Cu          // E8M0 scale 2^-3 (B pre-scaled x 8)

// ---- normalize inputs, scale by K2C, convert to fp8 e4m3; also picked ----
__global__ void k_prep(const float* __restrict__ X, const int* __restrict__ idx,
                       const int* __restrict__ lab, const float* __restrict__ F,
                       unsigned short* __restrict__ A8, float* __restrict__ picked) {
  int wid = threadIdx.x >> 6, lane = threadIdx.x & 63;
  int row = blockIdx.x * 4 + wid;
  int t = lab[idx[row]];
  float2 v = ((const float2*)(X + (size_t)row * 128))[lane];
  float2 f = ((const float2*)(F + (size_t)t * 128))[lane];
  float ss = v.x * v.x + v.y * v.y;
  float dp = v.x * f.x + v.y * f.y;
#pragma unroll
  for (int m = 1; m < 64; m <<= 1) {
    ss += __shfl_xor(ss, m, 64);
    dp += __shfl_xor(dp, m, 64);
  }
  float invn = 1.0f / fmaxf(sqrtf(ss), 1e-12f);
  float s = invn * K2C;               // fold 20*log2(e) into A
  int w = __builtin_amdgcn_cvt_pk_fp8_f32(v.x * s, v.y * s, 0, false);
  A8[row * 64 + lane] = (unsigned short)(w & 0xFFFF);
  if (lane == 0) picked[row] = 20.0f * dp * invn;
}

// ---- convert features f32 -> fp8 e4m3 (x8), zero-pad [100000,100352) ----
__global__ void k_conv(const float* __restrict__ F, unsigned char* __restrict__ Fq) {
  const int NG8 = NPAD * 16;     // 1,605,632 groups of 8 bytes
  const int NV8 = NCOLS * 16;    // 1,600,000 valid groups
  int stride = gridDim.x * blockDim.x;
  for (int g = blockIdx.x * blockDim.x + threadIdx.x; g < NG8; g += stride) {
    float4 a = make_float4(0.f, 0.f, 0.f, 0.f), b = a;
    if (g < NV8) {
      a = ((const float4*)F)[2 * g];
      b = ((const float4*)F)[2 * g + 1];
    }
    int w0 = __builtin_amdgcn_cvt_pk_fp8_f32(a.x * 8.f, a.y * 8.f, 0, false);
    w0 = __builtin_amdgcn_cvt_pk_fp8_f32(a.z * 8.f, a.w * 8.f, w0, true);
    int w1 = __builtin_amdgcn_cvt_pk_fp8_f32(b.x * 8.f, b.y * 8.f, 0, false);
    w1 = __builtin_amdgcn_cvt_pk_fp8_f32(b.z * 8.f, b.w * 8.f, w1, true);
    ((int2*)Fq)[g] = make_int2(w0, w1);
  }
}

// ---- fused GEMM + sum of exp(logit - 20), MX-fp8 K=128, fat blocks ----
// grid = 208 = 8 xcd * 26 slots; BM=1024 rows x 1024 cols per block; the 2
// blocks of a chunk share one XCD. Per-XCD blocks (<=26) <= 32 CUs -> the
// whole grid is co-resident in ONE round at 1 block/CU (16 waves, VGPR<=128).
// Ring of 3 x 8KB half-buffers; 2 halves in flight; ONE barrier per half;
// 4 free-flow phases inside (2 ds_read_b128 + 4 mfma_scale + 16 exp2 each).
__global__ __launch_bounds__(1024, 1) void k_gemm(
    const unsigned short* __restrict__ A8,
    const unsigned char* __restrict__ Fq,
    float* __restrict__ part) {
  __shared__ unsigned char ring[3][64 * 128];     // 24 KB ring (fp8)
  __shared__ float xpose[16][64];                 // part-store transpose
  const int tid = threadIdx.x;
  const int wid = tid >> 6, lane = tid & 63;
  const int lrow = lane & 15, lk = lane >> 4;

  const int slot = blockIdx.x >> 3;     // [0,26)
  const int xcd  = blockIdx.x & 7;
  const int mhalf = slot & 1;
  const int chunk = (slot >> 1) * 8 + xcd;
  if (chunk >= NCHUNK) return;
  const int row0 = mhalf * 1024 + wid * 64;

  // A fragments: 32 fp8 (full K strip) per lane per mf-tile = 32 VGPR total
  const unsigned char* A8b = (const unsigned char*)A8;
  int8v af[4];
#pragma unroll
  for (int mf = 0; mf < 4; ++mf) {
    const unsigned char* ap = A8b + (size_t)(row0 + mf * 16 + lrow) * 128 + lk * 32;
    int4v lo = *(const int4v*)ap;
    int4v hi = *(const int4v*)(ap + 16);
    af[mf][0] = lo[0]; af[mf][1] = lo[1]; af[mf][2] = lo[2]; af[mf][3] = lo[3];
    af[mf][4] = hi[0]; af[mf][5] = hi[1]; af[mf][6] = hi[2]; af[mf][7] = hi[3];
  }

  float racc[4][4];
#pragma unroll
  for (int mf = 0; mf < 4; ++mf)
#pragma unroll
    for (int j = 0; j < 4; ++j) racc[mf][j] = 0.f;

  const int nbase = chunk * 1024;

  // stage one half (512 x 16B units): threads 0..511 issue ONE gl_lds each.
  // LDS 16B-unit swizzle: phys u_p holds logical u_l = u_p ^ (col&7).
  auto issueHalf = [&](unsigned char* dst, int h) {
    if (tid < 512) {
      int off16 = tid;
      int col = off16 >> 3, up = off16 & 7;
      int ul = up ^ (col & 7);
      const unsigned char* src = Fq + (size_t)(nbase + h * 64 + col) * 128 + ul * 16;
      __builtin_amdgcn_global_load_lds((const AS1 void*)src,
                                       (AS3 void*)(dst + off16 * 16), 16, 0, 0);
    }
  };

  // 4 free-flow phases of one half; stage h+2 at phase 0
  auto half_body = [&](const unsigned char* sb, unsigned char* stDst, int hst) {
#pragma unroll
    for (int j = 0; j < 4; ++j) {
      int c = j * 16 + lrow;
      const unsigned char* cb = sb + c * 128;
      int x = c & 7;
      int4v lo = *(const int4v*)(cb + (((lk * 2)     ^ x) * 16));
      int4v hi = *(const int4v*)(cb + (((lk * 2 + 1) ^ x) * 16));
      int8v b8;
      b8[0] = lo[0]; b8[1] = lo[1]; b8[2] = lo[2]; b8[3] = lo[3];
      b8[4] = hi[0]; b8[5] = hi[1]; b8[6] = hi[2]; b8[7] = hi[3];
      if (stDst && j == 0) issueHalf(stDst, hst);
      f32x4 acc[4];
#pragma unroll
      for (int mf = 0; mf < 4; ++mf)
        acc[mf] = (f32x4){-K2C, -K2C, -K2C, -K2C};   // fold the -20 shift
      __builtin_amdgcn_s_setprio(1);
#pragma unroll
      for (int mf = 0; mf < 4; ++mf)
        acc[mf] = __builtin_amdgcn_mfma_scale_f32_16x16x128_f8f6f4(
            af[mf], b8, acc[mf], 0, 0, 0, SCLA, 0, SCLB);
      __builtin_amdgcn_s_setprio(0);
      // acc holds (20*cos - 20)*log2e: one exp2 per logit
#pragma unroll
      for (int mf = 0; mf < 4; ++mf)
#pragma unroll
        for (int jj = 0; jj < 4; ++jj)
          racc[mf][jj] += __builtin_amdgcn_exp2f(acc[mf][jj]);
    }
  };

  // prologue: 2 halves in flight (1 load/thread each for tid<512)
  issueHalf(&ring[0][0], 0);
  issueHalf(&ring[1][0], 1);

  int rs = 0;                          // read slot = h % 3
#pragma unroll 1
  for (int h = 0; h < 14; ++h) {
    // retire half h's load (keep h+1's in flight); barrier gives cross-wave
    // visibility AND protects ring slot (h+2 == h-1 mod 3) reuse
    asm volatile("s_waitcnt vmcnt(1)" ::: "memory");
    __builtin_amdgcn_s_barrier();
    int ss = rs + 2 - (rs >= 1 ? 3 : 0);          // (rs+2) % 3
    half_body(&ring[rs][0], &ring[ss][0], h + 2); // stages h+2 (<= 15)
    rs = (rs == 2) ? 0 : rs + 1;
  }
  asm volatile("s_waitcnt vmcnt(1)" ::: "memory");
  __builtin_amdgcn_s_barrier();
  half_body(&ring[rs][0], nullptr, 0);            // h = 14
  rs = (rs == 2) ? 0 : rs + 1;
  asm volatile("s_waitcnt vmcnt(0)" ::: "memory");
  __builtin_amdgcn_s_barrier();
  half_body(&ring[rs][0], nullptr, 0);            // h = 15

  // reduce across 16 lanes per row, transpose via LDS, coalesced store
#pragma unroll
  for (int mf = 0; mf < 4; ++mf)
#pragma unroll
    for (int j = 0; j < 4; ++j) {
      float v = racc[mf][j];
      v += __shfl_xor(v, 1, 64);
      v += __shfl_xor(v, 2, 64);
      v += __shfl_xor(v, 4, 64);
      v += __shfl_xor(v, 8, 64);
      if (lrow == 0) xpose[wid][mf * 16 + lk * 4 + j] = v;
    }
  __syncthreads();
  part[(size_t)chunk * NROWS + row0 + lane] = xpose[wid][lane];
}

// ---- stage 1 reduction: 56 blocks, each sums 14 chunks for 256 rows ----
__global__ void k_loss1(const float* __restrict__ part, float* __restrict__ psum) {
  int rb = blockIdx.x & 7, cb = blockIdx.x >> 3;   // cb in [0,7)
  int b = rb * 256 + threadIdx.x;
  float s = 0.f;
#pragma unroll
  for (int k = 0; k < 14; ++k)
    s += part[(size_t)(cb * 14 + k) * NROWS + b];
  psum[(size_t)cb * NROWS + b] = s;
}

// ---- final: per-row logz - picked, mean ----
__global__ void k_final(const float* __restrict__ psum, const float* __restrict__ picked,
                        float* __restrict__ out) {
  int tid = threadIdx.x;
  float lb = 0.f;
#pragma unroll
  for (int rr = 0; rr < 2; ++rr) {
    int b = rr * 1024 + tid;
    float tot = 0.f;
#pragma unroll
    for (int cb = 0; cb < 7; ++cb) tot += psum[(size_t)cb * NROWS + b];
    tot -= PADC;                     // remove pad-column contribution
    lb += 20.0f + logf(tot) - picked[b];
  }
#pragma unroll
  for (int m = 1; m < 64; m <<= 1) lb += __shfl_xor(lb, m, 64);
  __shared__ float red[16];
  if ((tid & 63) == 0) red[tid >> 6] = lb;
  __syncthreads();
  if (tid == 0) {
    float s = 0.f;
#pragma unroll
    for (int i = 0; i < 16; ++i) s += red[i];
    out[0] = s * (1.0f / 2048.0f);
  }
}

extern "C" void kernel_launch(void* const* d_in, const int* in_sizes, int n_in,
                              void* d_out, int out_size, void* d_ws, size_t ws_size,
                              hipStream_t stream) {
  const float* inputs  = (const float*)d_in[0];
  const int*   indexes = (const int*)d_in[1];
  const int*   labels  = (const int*)d_in[2];
  const float* feats   = (const float*)d_in[3];
  float* out = (float*)d_out;

  char* ws = (char*)d_ws;
  unsigned short* A8 = (unsigned short*)(ws + 0);        // 2048*128   = 262,144 B
  unsigned char*  Fq = (unsigned char*)(ws + 262144);    // 100352*128 = 12,845,056 B
  float* part   = (float*)(ws + 13107200);               // 98*2048*4  = 802,816 B
  float* psum   = (float*)(ws + 13910016);               // 7*2048*4   = 57,344 B
  float* picked = (float*)(ws + 13967360);               // 2048*4

  hipLaunchKernelGGL(k_prep,  dim3(512),  dim3(256),  0, stream, inputs, indexes, labels, feats, A8, picked);
  hipLaunchKernelGGL(k_conv,  dim3(2048), dim3(256),  0, stream, feats, Fq);
  hipLaunchKernelGGL(k_gemm,  dim3(208),  dim3(1024), 0, stream, A8, Fq, part);
  hipLaunchKernelGGL(k_loss1, dim3(56),   dim3(256),  0, stream, part, psum);
  hipLaunchKernelGGL(k_final, dim3(1),    dim3(1024), 0, stream, psum, picked, out);
}

// Round 18
// 67.389 us; speedup vs baseline: 2.1120x; 2.1120x over previous
//
#include <hip/hip_runtime.h>

typedef float f32x4 __attribute__((ext_vector_type(4)));
typedef int   int4v __attribute__((ext_vector_type(4)));
typedef int   int8v __attribute__((ext_vector_type(8)));

#define AS1 __attribute__((address_space(1)))
#define AS3 __attribute__((address_space(3)))

#define NROWS 2048
#define NCOLS 100000
#define NPAD  100352              // 98 chunks * 1024
#define NCHUNK 98
#define K2C  28.853900817779268f  // 20 * log2(e)
#define PADC 7.2552607e-7f        // 352 * exp(-20): pad-column bias
#define SCLA 0x7F7F7F7Fu          // E8M0 scale 2^0  (A already x K2C)
#define SCLB 0x7C7C7C7Cu          // E8M0 scale 2^-3 (B pre-scaled x 8)

// ---- normalize inputs, scale by K2C, convert to fp8 e4m3; also picked ----
__global__ void k_prep(const float* __restrict__ X, const int* __restrict__ idx,
                       const int* __restrict__ lab, const float* __restrict__ F,
                       unsigned short* __restrict__ A8, float* __restrict__ picked) {
  int wid = threadIdx.x >> 6, lane = threadIdx.x & 63;
  int row = blockIdx.x * 4 + wid;
  int t = lab[idx[row]];
  float2 v = ((const float2*)(X + (size_t)row * 128))[lane];
  float2 f = ((const float2*)(F + (size_t)t * 128))[lane];
  float ss = v.x * v.x + v.y * v.y;
  float dp = v.x * f.x + v.y * f.y;
#pragma unroll
  for (int m = 1; m < 64; m <<= 1) {
    ss += __shfl_xor(ss, m, 64);
    dp += __shfl_xor(dp, m, 64);
  }
  float invn = 1.0f / fmaxf(sqrtf(ss), 1e-12f);
  float s = invn * K2C;               // fold 20*log2(e) into A
  int w = __builtin_amdgcn_cvt_pk_fp8_f32(v.x * s, v.y * s, 0, false);
  A8[row * 64 + lane] = (unsigned short)(w & 0xFFFF);
  if (lane == 0) picked[row] = 20.0f * dp * invn;
}

// ---- convert features f32 -> fp8 e4m3 (x8), zero-pad [100000,100352) ----
__global__ void k_conv(const float* __restrict__ F, unsigned char* __restrict__ Fq) {
  const int NG8 = NPAD * 16;     // 1,605,632 groups of 8 bytes
  const int NV8 = NCOLS * 16;    // 1,600,000 valid groups
  int stride = gridDim.x * blockDim.x;
  for (int g = blockIdx.x * blockDim.x + threadIdx.x; g < NG8; g += stride) {
    float4 a = make_float4(0.f, 0.f, 0.f, 0.f), b = a;
    if (g < NV8) {
      a = ((const float4*)F)[2 * g];
      b = ((const float4*)F)[2 * g + 1];
    }
    int w0 = __builtin_amdgcn_cvt_pk_fp8_f32(a.x * 8.f, a.y * 8.f, 0, false);
    w0 = __builtin_amdgcn_cvt_pk_fp8_f32(a.z * 8.f, a.w * 8.f, w0, true);
    int w1 = __builtin_amdgcn_cvt_pk_fp8_f32(b.x * 8.f, b.y * 8.f, 0, false);
    w1 = __builtin_amdgcn_cvt_pk_fp8_f32(b.z * 8.f, b.w * 8.f, w1, true);
    ((int2*)Fq)[g] = make_int2(w0, w1);
  }
}

// ---- fused GEMM + sum of exp(logit - 20), MX-fp8 K=128 in ONE MFMA ----
// grid = 832 = 8 xcd * 104 slots; all 8 m-tiles of a chunk share one XCD.
// Ring of 3 x 8KB half-buffers (25 KB LDS); 2 halves in flight (vmcnt(2));
// ONE barrier per half; 4 free-flow phases inside. NO setprio: prio-1 MFMA
// windows starve co-resident waves' VALU/trans issue (T5 harmful on
// non-phase-split GEMM, m190) — removing it lets pipes overlap across waves.
__global__ __launch_bounds__(256, 2) void k_gemm(
    const unsigned short* __restrict__ A8,
    const unsigned char* __restrict__ Fq,
    float* __restrict__ part) {
  __shared__ unsigned char ring[3][64 * 128];     // 24 KB ring (fp8)
  __shared__ float xpose[4][64];                  // part-store transpose
  const int tid = threadIdx.x;
  const int wid = tid >> 6, lane = tid & 63;
  const int lrow = lane & 15, lk = lane >> 4;

  const int slot = blockIdx.x >> 3;     // [0,104)
  const int xcd  = blockIdx.x & 7;
  const int mtile = slot & 7;
  const int chunk = (slot >> 3) * 8 + xcd;
  if (chunk >= NCHUNK) return;
  const int row0 = mtile * 256 + wid * 64;

  // A fragments: 32 fp8 (full K strip) per lane per mf-tile = 32 VGPR total
  const unsigned char* A8b = (const unsigned char*)A8;
  int8v af[4];
#pragma unroll
  for (int mf = 0; mf < 4; ++mf) {
    const unsigned char* ap = A8b + (size_t)(row0 + mf * 16 + lrow) * 128 + lk * 32;
    int4v lo = *(const int4v*)ap;
    int4v hi = *(const int4v*)(ap + 16);
    af[mf][0] = lo[0]; af[mf][1] = lo[1]; af[mf][2] = lo[2]; af[mf][3] = lo[3];
    af[mf][4] = hi[0]; af[mf][5] = hi[1]; af[mf][6] = hi[2]; af[mf][7] = hi[3];
  }

  float racc[4][4];
#pragma unroll
  for (int mf = 0; mf < 4; ++mf)
#pragma unroll
    for (int j = 0; j < 4; ++j) racc[mf][j] = 0.f;

  const int nbase = chunk * 1024;

  // one global_load_lds (16B/thread) for half h: 2 per thread per half.
  // LDS 16B-unit swizzle: phys u_p holds logical u_l = u_p ^ (col&7).
  auto issue1 = [&](unsigned char* dst, int h, int it) {
    int off16 = it * 256 + tid;          // [0,512) 16B units
    int col = off16 >> 3, up = off16 & 7;
    int ul = up ^ (col & 7);
    const unsigned char* src = Fq + (size_t)(nbase + h * 64 + col) * 128 + ul * 16;
    __builtin_amdgcn_global_load_lds((const AS1 void*)src,
                                     (AS3 void*)(dst + off16 * 16), 16, 0, 0);
  };

  // 4 phases of one half; stage h+2 (2 issues) at phases 0 and 2
  auto half_body = [&](const unsigned char* sb, unsigned char* stDst, int hst) {
#pragma unroll
    for (int j = 0; j < 4; ++j) {
      int c = j * 16 + lrow;
      const unsigned char* cb = sb + c * 128;
      int x = c & 7;
      int4v lo = *(const int4v*)(cb + (((lk * 2)     ^ x) * 16));
      int4v hi = *(const int4v*)(cb + (((lk * 2 + 1) ^ x) * 16));
      int8v b8;
      b8[0] = lo[0]; b8[1] = lo[1]; b8[2] = lo[2]; b8[3] = lo[3];
      b8[4] = hi[0]; b8[5] = hi[1]; b8[6] = hi[2]; b8[7] = hi[3];
      if (stDst && (j & 1) == 0) issue1(stDst, hst, j >> 1);
      f32x4 acc[4];
#pragma unroll
      for (int mf = 0; mf < 4; ++mf)
        acc[mf] = (f32x4){-K2C, -K2C, -K2C, -K2C};   // fold the -20 shift
#pragma unroll
      for (int mf = 0; mf < 4; ++mf)
        acc[mf] = __builtin_amdgcn_mfma_scale_f32_16x16x128_f8f6f4(
            af[mf], b8, acc[mf], 0, 0, 0, SCLA, 0, SCLB);
      // acc holds (20*cos - 20)*log2e: one exp2 per logit
#pragma unroll
      for (int mf = 0; mf < 4; ++mf)
#pragma unroll
        for (int jj = 0; jj < 4; ++jj)
          racc[mf][jj] += __builtin_amdgcn_exp2f(acc[mf][jj]);
    }
  };

  // prologue: 2 halves in flight (4 loads/thread)
#pragma unroll
  for (int h = 0; h < 2; ++h)
#pragma unroll
    for (int it = 0; it < 2; ++it) issue1(&ring[h][0], h, it);

  int rs = 0;                          // read slot = h % 3
#pragma unroll 1
  for (int h = 0; h < 14; ++h) {
    // retire half h's 2 loads (keep h+1's in flight); barrier gives
    // cross-wave visibility AND protects ring slot (h+2 == h-1 mod 3)
    asm volatile("s_waitcnt vmcnt(2)" ::: "memory");
    __builtin_amdgcn_s_barrier();
    int ss = rs + 2 - (rs >= 1 ? 3 : 0);          // (rs+2) % 3
    half_body(&ring[rs][0], &ring[ss][0], h + 2); // stages h+2 (<= 15)
    rs = (rs == 2) ? 0 : rs + 1;
  }
  asm volatile("s_waitcnt vmcnt(2)" ::: "memory");
  __builtin_amdgcn_s_barrier();
  half_body(&ring[rs][0], nullptr, 0);            // h = 14
  rs = (rs == 2) ? 0 : rs + 1;
  asm volatile("s_waitcnt vmcnt(0)" ::: "memory");
  __builtin_amdgcn_s_barrier();
  half_body(&ring[rs][0], nullptr, 0);            // h = 15

  // reduce across 16 lanes per row, transpose via LDS, coalesced store
#pragma unroll
  for (int mf = 0; mf < 4; ++mf)
#pragma unroll
    for (int j = 0; j < 4; ++j) {
      float v = racc[mf][j];
      v += __shfl_xor(v, 1, 64);
      v += __shfl_xor(v, 2, 64);
      v += __shfl_xor(v, 4, 64);
      v += __shfl_xor(v, 8, 64);
      if (lrow == 0) xpose[wid][mf * 16 + lk * 4 + j] = v;
    }
  __syncthreads();
  part[(size_t)chunk * NROWS + row0 + lane] = xpose[wid][lane];
}

// ---- stage 1 reduction: 56 blocks, each sums 14 chunks for 256 rows ----
__global__ void k_loss1(const float* __restrict__ part, float* __restrict__ psum) {
  int rb = blockIdx.x & 7, cb = blockIdx.x >> 3;   // cb in [0,7)
  int b = rb * 256 + threadIdx.x;
  float s = 0.f;
#pragma unroll
  for (int k = 0; k < 14; ++k)
    s += part[(size_t)(cb * 14 + k) * NROWS + b];
  psum[(size_t)cb * NROWS + b] = s;
}

// ---- final: per-row logz - picked, mean ----
__global__ void k_final(const float* __restrict__ psum, const float* __restrict__ picked,
                        float* __restrict__ out) {
  int tid = threadIdx.x;
  float lb = 0.f;
#pragma unroll
  for (int rr = 0; rr < 2; ++rr) {
    int b = rr * 1024 + tid;
    float tot = 0.f;
#pragma unroll
    for (int cb = 0; cb < 7; ++cb) tot += psum[(size_t)cb * NROWS + b];
    tot -= PADC;                     // remove pad-column contribution
    lb += 20.0f + logf(tot) - picked[b];
  }
#pragma unroll
  for (int m = 1; m < 64; m <<= 1) lb += __shfl_xor(lb, m, 64);
  __shared__ float red[16];
  if ((tid & 63) == 0) red[tid >> 6] = lb;
  __syncthreads();
  if (tid == 0) {
    float s = 0.f;
#pragma unroll
    for (int i = 0; i < 16; ++i) s += red[i];
    out[0] = s * (1.0f / 2048.0f);
  }
}

extern "C" void kernel_launch(void* const* d_in, const int* in_sizes, int n_in,
                              void* d_out, int out_size, void* d_ws, size_t ws_size,
                              hipStream_t stream) {
  const float* inputs  = (const float*)d_in[0];
  const int*   indexes = (const int*)d_in[1];
  const int*   labels  = (const int*)d_in[2];
  const float* feats   = (const float*)d_in[3];
  float* out = (float*)d_out;

  char* ws = (char*)d_ws;
  unsigned short* A8 = (unsigned short*)(ws + 0);        // 2048*128   = 262,144 B
  unsigned char*  Fq = (unsigned char*)(ws + 262144);    // 100352*128 = 12,845,056 B
  float* part   = (float*)(ws + 13107200);               // 98*2048*4  = 802,816 B
  float* psum   = (float*)(ws + 13910016);               // 7*2048*4   = 57,344 B
  float* picked = (float*)(ws + 13967360);               // 2048*4

  hipLaunchKernelGGL(k_prep,  dim3(512),  dim3(256),  0, stream, inputs, indexes, labels, feats, A8, picked);
  hipLaunchKernelGGL(k_conv,  dim3(2048), dim3(256),  0, stream, feats, Fq);
  hipLaunchKernelGGL(k_gemm,  dim3(832),  dim3(256),  0, stream, A8, Fq, part);
  hipLaunchKernelGGL(k_loss1, dim3(56),   dim3(256),  0, stream, part, psum);
  hipLaunchKernelGGL(k_final, dim3(1),    dim3(1024), 0, stream, psum, picked, out);
}

// Round 19
// 67.292 us; speedup vs baseline: 2.1151x; 1.0014x over previous
//
#include <hip/hip_runtime.h>

typedef float f32x4 __attribute__((ext_vector_type(4)));
typedef int   int4v __attribute__((ext_vector_type(4)));
typedef int   int8v __attribute__((ext_vector_type(8)));

#define AS1 __attribute__((address_space(1)))
#define AS3 __attribute__((address_space(3)))

#define NROWS 2048
#define NCOLS 100000
#define NPAD  100352              // 98 chunks * 1024
#define NCHUNK 98
#define K2C  28.853900817779268f  // 20 * log2(e)
#define PADC 7.2552607e-7f        // 352 * exp(-20): pad-column bias
#define SCLA 0x7F7F7F7Fu          // E8M0 scale 2^0  (A already x K2C)
#define SCLB 0x7C7C7C7Cu          // E8M0 scale 2^-3 (B pre-scaled x 8)

// ---- normalize inputs, scale by K2C, convert to fp8 e4m3; also picked ----
__global__ void k_prep(const float* __restrict__ X, const int* __restrict__ idx,
                       const int* __restrict__ lab, const float* __restrict__ F,
                       unsigned short* __restrict__ A8, float* __restrict__ picked) {
  int wid = threadIdx.x >> 6, lane = threadIdx.x & 63;
  int row = blockIdx.x * 4 + wid;
  int t = lab[idx[row]];
  float2 v = ((const float2*)(X + (size_t)row * 128))[lane];
  float2 f = ((const float2*)(F + (size_t)t * 128))[lane];
  float ss = v.x * v.x + v.y * v.y;
  float dp = v.x * f.x + v.y * f.y;
#pragma unroll
  for (int m = 1; m < 64; m <<= 1) {
    ss += __shfl_xor(ss, m, 64);
    dp += __shfl_xor(dp, m, 64);
  }
  float invn = 1.0f / fmaxf(sqrtf(ss), 1e-12f);
  float s = invn * K2C;               // fold 20*log2(e) into A
  int w = __builtin_amdgcn_cvt_pk_fp8_f32(v.x * s, v.y * s, 0, false);
  A8[row * 64 + lane] = (unsigned short)(w & 0xFFFF);
  if (lane == 0) picked[row] = 20.0f * dp * invn;
}

// ---- convert features f32 -> fp8 e4m3 (x8), zero-pad [100000,100352) ----
__global__ void k_conv(const float* __restrict__ F, unsigned char* __restrict__ Fq) {
  const int NG8 = NPAD * 16;     // 1,605,632 groups of 8 bytes
  const int NV8 = NCOLS * 16;    // 1,600,000 valid groups
  int stride = gridDim.x * blockDim.x;
  for (int g = blockIdx.x * blockDim.x + threadIdx.x; g < NG8; g += stride) {
    float4 a = make_float4(0.f, 0.f, 0.f, 0.f), b = a;
    if (g < NV8) {
      a = ((const float4*)F)[2 * g];
      b = ((const float4*)F)[2 * g + 1];
    }
    int w0 = __builtin_amdgcn_cvt_pk_fp8_f32(a.x * 8.f, a.y * 8.f, 0, false);
    w0 = __builtin_amdgcn_cvt_pk_fp8_f32(a.z * 8.f, a.w * 8.f, w0, true);
    int w1 = __builtin_amdgcn_cvt_pk_fp8_f32(b.x * 8.f, b.y * 8.f, 0, false);
    w1 = __builtin_amdgcn_cvt_pk_fp8_f32(b.z * 8.f, b.w * 8.f, w1, true);
    ((int2*)Fq)[g] = make_int2(w0, w1);
  }
}

// ---- fused GEMM + sum of exp(logit - 20), MX-fp8 K=128 in ONE MFMA ----
// grid = 832 = 8 xcd * 104 slots; all 8 m-tiles of a chunk share one XCD.
// Ring of 3 x 8KB half-buffers (25 KB LDS); 2 halves in flight (vmcnt(2));
// ONE barrier per half; 4 free-flow phases inside; no setprio (r18).
// Constant-C MFMA: C operand is a hoisted loop-invariant register block
// (D != C is legal), eliminating 16 acc-init v_movs per phase.
__global__ __launch_bounds__(256, 2) void k_gemm(
    const unsigned short* __restrict__ A8,
    const unsigned char* __restrict__ Fq,
    float* __restrict__ part) {
  __shared__ unsigned char ring[3][64 * 128];     // 24 KB ring (fp8)
  __shared__ float xpose[4][64];                  // part-store transpose
  const int tid = threadIdx.x;
  const int wid = tid >> 6, lane = tid & 63;
  const int lrow = lane & 15, lk = lane >> 4;

  const int slot = blockIdx.x >> 3;     // [0,104)
  const int xcd  = blockIdx.x & 7;
  const int mtile = slot & 7;
  const int chunk = (slot >> 3) * 8 + xcd;
  if (chunk >= NCHUNK) return;
  const int row0 = mtile * 256 + wid * 64;

  // A fragments: 32 fp8 (full K strip) per lane per mf-tile = 32 VGPR total
  const unsigned char* A8b = (const unsigned char*)A8;
  int8v af[4];
#pragma unroll
  for (int mf = 0; mf < 4; ++mf) {
    const unsigned char* ap = A8b + (size_t)(row0 + mf * 16 + lrow) * 128 + lk * 32;
    ((int4v*)&af[mf])[0] = *(const int4v*)ap;
    ((int4v*)&af[mf])[1] = *(const int4v*)(ap + 16);
  }

  float racc[4][4];
#pragma unroll
  for (int mf = 0; mf < 4; ++mf)
#pragma unroll
    for (int j = 0; j < 4; ++j) racc[mf][j] = 0.f;

  // loop-invariant C operand: folds the -20 shift with ZERO per-phase movs
  f32x4 cinit = (f32x4){-K2C, -K2C, -K2C, -K2C};

  const int nbase = chunk * 1024;

  // one global_load_lds (16B/thread) for half h: 2 per thread per half.
  // LDS 16B-unit swizzle: phys u_p holds logical u_l = u_p ^ (col&7).
  auto issue1 = [&](unsigned char* dst, int h, int it) {
    int off16 = it * 256 + tid;          // [0,512) 16B units
    int col = off16 >> 3, up = off16 & 7;
    int ul = up ^ (col & 7);
    const unsigned char* src = Fq + (size_t)(nbase + h * 64 + col) * 128 + ul * 16;
    __builtin_amdgcn_global_load_lds((const AS1 void*)src,
                                     (AS3 void*)(dst + off16 * 16), 16, 0, 0);
  };

  // 4 phases of one half; stage h+2 (2 issues) at phases 0 and 2
  auto half_body = [&](const unsigned char* sb, unsigned char* stDst, int hst) {
#pragma unroll
    for (int j = 0; j < 4; ++j) {
      int c = j * 16 + lrow;
      const unsigned char* cb = sb + c * 128;
      int x = c & 7;
      int8v b8;
      ((int4v*)&b8)[0] = *(const int4v*)(cb + (((lk * 2)     ^ x) * 16));
      ((int4v*)&b8)[1] = *(const int4v*)(cb + (((lk * 2 + 1) ^ x) * 16));
      if (stDst && (j & 1) == 0) issue1(stDst, hst, j >> 1);
      f32x4 acc[4];
#pragma unroll
      for (int mf = 0; mf < 4; ++mf)
        acc[mf] = __builtin_amdgcn_mfma_scale_f32_16x16x128_f8f6f4(
            af[mf], b8, cinit, 0, 0, 0, SCLA, 0, SCLB);
      // acc holds (20*cos - 20)*log2e: one exp2 per logit
#pragma unroll
      for (int mf = 0; mf < 4; ++mf)
#pragma unroll
        for (int jj = 0; jj < 4; ++jj)
          racc[mf][jj] += __builtin_amdgcn_exp2f(acc[mf][jj]);
    }
  };

  // prologue: 2 halves in flight (4 loads/thread)
#pragma unroll
  for (int h = 0; h < 2; ++h)
#pragma unroll
    for (int it = 0; it < 2; ++it) issue1(&ring[h][0], h, it);

  int rs = 0;                          // read slot = h % 3
#pragma unroll 1
  for (int h = 0; h < 14; ++h) {
    // retire half h's 2 loads (keep h+1's in flight); barrier gives
    // cross-wave visibility AND protects ring slot (h+2 == h-1 mod 3)
    asm volatile("s_waitcnt vmcnt(2)" ::: "memory");
    __builtin_amdgcn_s_barrier();
    int ss = rs + 2 - (rs >= 1 ? 3 : 0);          // (rs+2) % 3
    half_body(&ring[rs][0], &ring[ss][0], h + 2); // stages h+2 (<= 15)
    rs = (rs == 2) ? 0 : rs + 1;
  }
  asm volatile("s_waitcnt vmcnt(2)" ::: "memory");
  __builtin_amdgcn_s_barrier();
  half_body(&ring[rs][0], nullptr, 0);            // h = 14
  rs = (rs == 2) ? 0 : rs + 1;
  asm volatile("s_waitcnt vmcnt(0)" ::: "memory");
  __builtin_amdgcn_s_barrier();
  half_body(&ring[rs][0], nullptr, 0);            // h = 15

  // reduce across 16 lanes per row, transpose via LDS, coalesced store
#pragma unroll
  for (int mf = 0; mf < 4; ++mf)
#pragma unroll
    for (int j = 0; j < 4; ++j) {
      float v = racc[mf][j];
      v += __shfl_xor(v, 1, 64);
      v += __shfl_xor(v, 2, 64);
      v += __shfl_xor(v, 4, 64);
      v += __shfl_xor(v, 8, 64);
      if (lrow == 0) xpose[wid][mf * 16 + lk * 4 + j] = v;
    }
  __syncthreads();
  part[(size_t)chunk * NROWS + row0 + lane] = xpose[wid][lane];
}

// ---- stage 1 reduction: 56 blocks, each sums 14 chunks for 256 rows ----
__global__ void k_loss1(const float* __restrict__ part, float* __restrict__ psum) {
  int rb = blockIdx.x & 7, cb = blockIdx.x >> 3;   // cb in [0,7)
  int b = rb * 256 + threadIdx.x;
  float s = 0.f;
#pragma unroll
  for (int k = 0; k < 14; ++k)
    s += part[(size_t)(cb * 14 + k) * NROWS + b];
  psum[(size_t)cb * NROWS + b] = s;
}

// ---- final: per-row logz - picked, mean ----
__global__ void k_final(const float* __restrict__ psum, const float* __restrict__ picked,
                        float* __restrict__ out) {
  int tid = threadIdx.x;
  float lb = 0.f;
#pragma unroll
  for (int rr = 0; rr < 2; ++rr) {
    int b = rr * 1024 + tid;
    float tot = 0.f;
#pragma unroll
    for (int cb = 0; cb < 7; ++cb) tot += psum[(size_t)cb * NROWS + b];
    tot -= PADC;                     // remove pad-column contribution
    lb += 20.0f + logf(tot) - picked[b];
  }
#pragma unroll
  for (int m = 1; m < 64; m <<= 1) lb += __shfl_xor(lb, m, 64);
  __shared__ float red[16];
  if ((tid & 63) == 0) red[tid >> 6] = lb;
  __syncthreads();
  if (tid == 0) {
    float s = 0.f;
#pragma unroll
    for (int i = 0; i < 16; ++i) s += red[i];
    out[0] = s * (1.0f / 2048.0f);
  }
}

extern "C" void kernel_launch(void* const* d_in, const int* in_sizes, int n_in,
                              void* d_out, int out_size, void* d_ws, size_t ws_size,
                              hipStream_t stream) {
  const float* inputs  = (const float*)d_in[0];
  const int*   indexes = (const int*)d_in[1];
  const int*   labels  = (const int*)d_in[2];
  const float* feats   = (const float*)d_in[3];
  float* out = (float*)d_out;

  char* ws = (char*)d_ws;
  unsigned short* A8 = (unsigned short*)(ws + 0);        // 2048*128   = 262,144 B
  unsigned char*  Fq = (unsigned char*)(ws + 262144);    // 100352*128 = 12,845,056 B
  float* part   = (float*)(ws + 13107200);               // 98*2048*4  = 802,816 B
  float* psum   = (float*)(ws + 13910016);               // 7*2048*4   = 57,344 B
  float* picked = (float*)(ws + 13967360);               // 2048*4

  hipLaunchKernelGGL(k_prep,  dim3(512),  dim3(256),  0, stream, inputs, indexes, labels, feats, A8, picked);
  hipLaunchKernelGGL(k_conv,  dim3(2048), dim3(256),  0, stream, feats, Fq);
  hipLaunchKernelGGL(k_gemm,  dim3(832),  dim3(256),  0, stream, A8, Fq, part);
  hipLaunchKernelGGL(k_loss1, dim3(56),   dim3(256),  0, stream, part, psum);
  hipLaunchKernelGGL(k_final, dim3(1),    dim3(1024), 0, stream, psum, picked, out);
}